// Round 9
// baseline (936.890 us; speedup 1.0000x reference)
//
#include <hip/hip_runtime.h>

// Problem: B=512, T=128, I=128, H=512 (fp32 in/out; bf16 MFMA internally)
#define HD 512
#define KD 640
#define G4 2048

typedef short short8 __attribute__((ext_vector_type(8)));
typedef __bf16 bf16x8 __attribute__((ext_vector_type(8)));
typedef float floatx4 __attribute__((ext_vector_type(4)));
typedef unsigned int uintx4 __attribute__((ext_vector_type(4)));

static __device__ __forceinline__ unsigned short f2bf(float f) {
  unsigned int u = __float_as_uint(f);
  u += 0x7fffu + ((u >> 16) & 1u);   // RNE
  return (unsigned short)(u >> 16);
}
static __device__ __forceinline__ float rcp_(float x) {
  return __builtin_amdgcn_rcpf(x);
}
static __device__ __forceinline__ float sigmoidf_(float x) {
  return rcp_(1.f + __expf(-x));
}
static __device__ __forceinline__ float tanhf_(float x) {
  float ax = fabsf(x);
  float e = __expf(-2.f * ax);
  float r = fmaf(-2.f * e, rcp_(1.f + e), 1.f);
  return copysignf(r, x);
}
// agent-coherent 16B store: sc0 sc1 = write-through to MALL
static __device__ __forceinline__ void store16_cc(unsigned long long a, uintx4 v) {
  asm volatile("global_store_dwordx4 %0, %1, off sc0 sc1" :: "v"(a), "v"(v) : "memory");
}
static __device__ __forceinline__ void waitcnt_vm0() {
  asm volatile("s_waitcnt vmcnt(0)" ::: "memory");
}
static __device__ __forceinline__ void waitcnt_vm4() {
  asm volatile("s_waitcnt vmcnt(4)" ::: "memory");
}
static __device__ __forceinline__ void raw_barrier() {
  asm volatile("s_barrier" ::: "memory");
}
// global -> LDS direct DMA, 16B/lane, SC0|SC1 (=17): bypass L1/L2, read at MALL
// (coherent with store16_cc). LDS dest = wave-uniform base + lane*16.
static __device__ __forceinline__ void load_lds16_cc(const void* g, void* l) {
  __builtin_amdgcn_global_load_lds(
      (const __attribute__((address_space(1))) void*)(unsigned long long)(uintptr_t)g,
      (__attribute__((address_space(3))) void*)l, 16, 0, 17);
}

// ---------------- prep: 3 weight transposes (fp32->bf16) + flag zeroing, fused
// grid 769: [0,320) sW, [320,640) lW, [640,768) oW, 768 = zero flags
__global__ __launch_bounds__(256) void prep(
    const float* __restrict__ sW, const float* __restrict__ lW,
    const float* __restrict__ oW,
    unsigned short* __restrict__ WTs, unsigned short* __restrict__ WTl,
    unsigned short* __restrict__ WTo, int* __restrict__ flags) {
  const int bx = blockIdx.x;
  const int tid = threadIdx.x;
  if (bx >= 768) {
    for (int i = tid; i < 1024; i += 256) flags[i] = 0;
    return;
  }
  __shared__ unsigned short tile[64][80];
  const float* src; unsigned short* dst; int R, C, idx;
  if (bx < 320)      { src = sW; dst = WTs; R = 640;  C = 2048; idx = bx; }
  else if (bx < 640) { src = lW; dst = WTl; R = 640;  C = 2048; idx = bx - 320; }
  else               { src = oW; dst = WTo; R = 1024; C = 512;  idx = bx - 640; }
  int nR = R >> 6;
  int tr = idx % nR, tc = idx / nR;
#pragma unroll
  for (int i = 0; i < 2; ++i) {
    int seg = tid + i * 256;
    int row = seg >> 3, ks8 = (seg & 7) * 8;
    const float* p = src + (size_t)(tr * 64 + row) * C + tc * 64 + ks8;
    short8 v;
#pragma unroll
    for (int q = 0; q < 8; ++q) v[q] = (short)f2bf(p[q]);
    *(short8*)(&tile[row][ks8]) = v;
  }
  __syncthreads();
#pragma unroll
  for (int i = 0; i < 2; ++i) {
    int seg = tid + i * 256;
    int cl = seg >> 3, rs8 = (seg & 7) * 8;
    short8 v;
#pragma unroll
    for (int q = 0; q < 8; ++q) v[q] = (short)tile[rs8 + q][cl];
    *(short8*)(dst + (size_t)(tc * 64 + cl) * R + tr * 64 + rs8) = v;
  }
}

// ---------------- persistent dual-LSTM over all 128 steps (two-phase pipelined)
// grid 256 = lstm(2) x mb(16: 32 rows) x nb(8: 64 h)
// wave wn owns h-cols [wn*16,+16) x ALL 4 gates — gate math lane-local.
// Per step: poll(32 per-wave flags) -> bar -> issue 8 h global_load_lds (rows
// ascending) -> x-MFMA kc0..3 -> vmcnt(4)+raw bar (rows 0..15 in) -> acc0
// h-MFMA -> vmcnt(0)+raw bar -> acc1 h-MFMA -> gate math -> bar -> h store
// -> own-wave vmcnt0 -> per-wave flag post -> x(t+1) staging (off flag path).
__global__ __launch_bounds__(256, 1) void lstm_persistent(
    const float* __restrict__ xs, const float* __restrict__ xl,
    const unsigned short* __restrict__ WTs, const unsigned short* __restrict__ WTl,
    const float* __restrict__ bs, const float* __restrict__ bl,
    unsigned short* __restrict__ hs0, unsigned short* __restrict__ hs1,
    unsigned short* __restrict__ hl0, unsigned short* __restrict__ hl1,
    int* __restrict__ flags) {
  const int bid = blockIdx.x;
  const int lstm = bid & 1;
  const int mb = (bid >> 1) & 15;
  const int nb = bid >> 5;
  const int grp = lstm * 16 + mb;          // 32 groups x 8 blocks
  const int b0 = mb * 32;
  const int H0 = nb * 64;

  const float* x = lstm ? xl : xs;         // fp32 [512][128][128]
  const unsigned short* WT = lstm ? WTl : WTs;
  const float* bias = lstm ? bl : bs;
  unsigned short* h0 = lstm ? hl0 : hs0;
  unsigned short* h1 = lstm ? hl1 : hs1;

  __shared__ unsigned short As[32][648];   // 41472 B; row stride 1296 B
  __shared__ unsigned short hbuf[32][72];  // 4608 B

  const int tid = threadIdx.x;
  const int wn = tid >> 6;
  const int lane = tid & 63;
  const int quad = lane >> 4;
  const int lrow = lane & 15;
  const int colL = wn * 16 + lrow;

  float bias_r[4];
#pragma unroll
  for (int g = 0; g < 4; ++g) bias_r[g] = bias[g * HD + H0 + colL];
  float c_r[8];
#pragma unroll
  for (int j = 0; j < 8; ++j) c_r[j] = 0.f;

  bf16x8 breg[4][20];
#pragma unroll
  for (int g = 0; g < 4; ++g) {
    const unsigned short* wp = WT + (size_t)(g * HD + H0 + colL) * KD + quad * 8;
#pragma unroll
    for (int kc = 0; kc < 20; ++kc)
      breg[g][kc] = __builtin_bit_cast(bf16x8, *(const short8*)(wp + kc * 32));
  }

  const int st_row = tid >> 3, st_c8 = (tid & 7) * 8;
  const unsigned long long hstA =
      (unsigned long long)(h1 + (size_t)(b0 + st_row) * HD + H0 + st_c8);  // t even
  const unsigned long long hstB =
      (unsigned long long)(h0 + (size_t)(b0 + st_row) * HD + H0 + st_c8);  // t odd

  // stage x_tt (fp32 -> bf16) into As cols [0,128)
  auto stage_x = [&](int tt) {
#pragma unroll
    for (int i = 0; i < 2; ++i) {
      int seg = tid + i * 256;
      int row = seg >> 4, ch = seg & 15;
      const float* p = x + (size_t)(b0 + row) * 16384 + tt * 128 + ch * 8;
      short8 v;
#pragma unroll
      for (int q = 0; q < 8; ++q) v[q] = (short)f2bf(p[q]);
      *(short8*)(&As[row][ch * 8]) = v;
    }
  };

  stage_x(0);   // prologue; t=0 skips h-MFMA entirely (h=0)

#pragma unroll 1
  for (int t = 0; t < 128; ++t) {
    const unsigned short* hr = (t & 1) ? h1 : h0;

    // (A) poll all 32 per-wave flags of this group
    if (t > 0 && wn == 0) {
      const int fidx = grp * 32 + (lane & 31);
      while (true) {
        int v = __hip_atomic_load(flags + fidx,
                                  __ATOMIC_RELAXED, __HIP_MEMORY_SCOPE_AGENT);
        if (__ballot(v >= t) == 0xFFFFFFFFFFFFFFFFull) break;
        __builtin_amdgcn_s_sleep(1);
      }
    }
    __syncthreads();   // (B) x(t) staged visible; flags passed

    // (C) issue h(t) -> LDS DMA, rows ascending (first 4 per wave = rows 0..15)
    if (t > 0) {
#pragma unroll
      for (int i = 0; i < 8; ++i) {
        int row = wn + i * 4;
        load_lds16_cc(hr + (size_t)(b0 + row) * HD + lane * 8, &As[row][128]);
      }
    }

    // (D) x-part MFMA (kc 0..3) while h loads are in flight
    floatx4 acc[2][4];
#pragma unroll
    for (int mt = 0; mt < 2; ++mt)
#pragma unroll
      for (int g = 0; g < 4; ++g) acc[mt][g] = (floatx4){0.f, 0.f, 0.f, 0.f};
#pragma unroll
    for (int kc = 0; kc < 4; ++kc) {
      bf16x8 a0 = __builtin_bit_cast(bf16x8, *(const short8*)(&As[lrow][kc * 32 + quad * 8]));
      bf16x8 a1 = __builtin_bit_cast(bf16x8, *(const short8*)(&As[16 + lrow][kc * 32 + quad * 8]));
#pragma unroll
      for (int g = 0; g < 4; ++g) {
        acc[0][g] = __builtin_amdgcn_mfma_f32_16x16x32_bf16(a0, breg[g][kc], acc[0][g], 0, 0, 0);
        acc[1][g] = __builtin_amdgcn_mfma_f32_16x16x32_bf16(a1, breg[g][kc], acc[1][g], 0, 0, 0);
      }
    }

    if (t > 0) {
      // (E) phase 1: rows 0..15 landed (own first-4 loads + barrier for peers)
      waitcnt_vm4();
      raw_barrier();
#pragma unroll
      for (int kc = 4; kc < 20; ++kc) {
        bf16x8 a0 = __builtin_bit_cast(bf16x8, *(const short8*)(&As[lrow][kc * 32 + quad * 8]));
#pragma unroll
        for (int g = 0; g < 4; ++g)
          acc[0][g] = __builtin_amdgcn_mfma_f32_16x16x32_bf16(a0, breg[g][kc], acc[0][g], 0, 0, 0);
      }
      // (F) phase 2: rows 16..31 landed
      waitcnt_vm0();
      raw_barrier();
#pragma unroll
      for (int kc = 4; kc < 20; ++kc) {
        bf16x8 a1 = __builtin_bit_cast(bf16x8, *(const short8*)(&As[16 + lrow][kc * 32 + quad * 8]));
#pragma unroll
        for (int g = 0; g < 4; ++g)
          acc[1][g] = __builtin_amdgcn_mfma_f32_16x16x32_bf16(a1, breg[g][kc], acc[1][g], 0, 0, 0);
      }
    }

    // (H) lane-local gate math -> hbuf
#pragma unroll
    for (int mt = 0; mt < 2; ++mt)
#pragma unroll
      for (int r = 0; r < 4; ++r) {
        int j = mt * 4 + r;
        float fg = acc[mt][0][r] + bias_r[0];
        float ig = acc[mt][1][r] + bias_r[1];
        float og = acc[mt][2][r] + bias_r[2];
        float cg = acc[mt][3][r] + bias_r[3];
        float cn = sigmoidf_(fg) * c_r[j] + sigmoidf_(ig) * tanhf_(cg);
        float hn = sigmoidf_(og) * tanhf_(cn);
        c_r[j] = cn;
        hbuf[mt * 16 + quad * 4 + r][colL] = f2bf(hn);
      }
    __syncthreads();   // (I) hbuf complete; all As reads done

    // (J) h store -> own-wave drain -> per-wave flag post (race-free, earliest)
    short8 hv8 = *(const short8*)(&hbuf[st_row][st_c8]);
    store16_cc((t & 1) ? hstB : hstA, __builtin_bit_cast(uintx4, hv8));
    waitcnt_vm0();
    if (lane == 0 && t < 127)
      __hip_atomic_store(flags + grp * 32 + nb * 4 + wn, t + 1,
                         __ATOMIC_RELAXED, __HIP_MEMORY_SCOPE_AGENT);
    // (K) x(t+1) staging, off the flag critical path
    if (t < 127) stage_x(t + 1);
  }
}

// ---------------- out = tanh(concat(hs,hl) @ out_W + out_b), fp32 out
__global__ __launch_bounds__(256) void out_gemm(
    const unsigned short* __restrict__ hs, const unsigned short* __restrict__ hl,
    const unsigned short* __restrict__ WTo,  // [512][1024] bf16
    const float* __restrict__ ob, float* __restrict__ out) {
  const int bx = blockIdx.x;
  const int mb = bx & 7;
  const int nb = bx >> 3;

  __shared__ unsigned short As2[64][88];
  __shared__ unsigned short Bs2[128][88];

  const int tid = threadIdx.x;
  const int wave = tid >> 6;
  const int lane = tid & 63;
  const int quad = lane >> 4;
  const int lrow = lane & 15;
  const int wm = wave & 1;
  const int wn = wave >> 1;

  floatx4 acc[8];
#pragma unroll
  for (int i = 0; i < 8; ++i) acc[i] = (floatx4){0.f, 0.f, 0.f, 0.f};

  for (int k0 = 0; k0 < 1024; k0 += 64) {
#pragma unroll
    for (int i = 0; i < 2; ++i) {
      int seg = tid + i * 256;
      int row = seg >> 3, ks8 = (seg & 7) * 8;
      int kg = k0 + ks8;
      int b = mb * 64 + row;
      const unsigned short* src =
          (kg < 512) ? (hs + (size_t)b * HD + kg) : (hl + (size_t)b * HD + (kg - 512));
      *(short8*)(&As2[row][ks8]) = *(const short8*)src;
    }
#pragma unroll
    for (int i = 0; i < 4; ++i) {
      int seg = tid + i * 256;
      int n = seg >> 3, ks8 = (seg & 7) * 8;
      *(short8*)(&Bs2[n][ks8]) =
          *(const short8*)(WTo + (size_t)(nb * 128 + n) * 1024 + k0 + ks8);
    }
    __syncthreads();
#pragma unroll
    for (int ks = 0; ks < 64; ks += 32) {
      int kq = ks + quad * 8;
      bf16x8 a0 = __builtin_bit_cast(bf16x8, *(const short8*)(&As2[wm * 32 + lrow][kq]));
      bf16x8 a1 = __builtin_bit_cast(bf16x8, *(const short8*)(&As2[wm * 32 + 16 + lrow][kq]));
#pragma unroll
      for (int nt = 0; nt < 4; ++nt) {
        bf16x8 bfr = __builtin_bit_cast(bf16x8, *(const short8*)(&Bs2[wn * 64 + nt * 16 + lrow][kq]));
        acc[nt] = __builtin_amdgcn_mfma_f32_16x16x32_bf16(a0, bfr, acc[nt], 0, 0, 0);
        acc[4 + nt] = __builtin_amdgcn_mfma_f32_16x16x32_bf16(a1, bfr, acc[4 + nt], 0, 0, 0);
      }
    }
    __syncthreads();
  }
#pragma unroll
  for (int mt = 0; mt < 2; ++mt) {
#pragma unroll
    for (int nt = 0; nt < 4; ++nt) {
      int n = nb * 128 + wn * 64 + nt * 16 + lrow;
      float bv = ob[n];
#pragma unroll
      for (int r = 0; r < 4; ++r) {
        int b = mb * 64 + wm * 32 + mt * 16 + quad * 4 + r;
        out[(size_t)b * HD + n] = tanhf_(acc[mt * 4 + nt][r] + bv);
      }
    }
  }
}

extern "C" void kernel_launch(void* const* d_in, const int* in_sizes, int n_in,
                              void* d_out, int out_size, void* d_ws, size_t ws_size,
                              hipStream_t stream) {
  (void)in_sizes; (void)n_in; (void)out_size; (void)ws_size;
  const float* xs = (const float*)d_in[0];
  const float* xl = (const float*)d_in[1];
  const float* sW = (const float*)d_in[4];
  const float* sb = (const float*)d_in[5];
  const float* lW = (const float*)d_in[6];
  const float* lb = (const float*)d_in[7];
  const float* oW = (const float*)d_in[8];
  const float* ob = (const float*)d_in[9];

  char* w = (char*)d_ws;
  int* flags = (int*)w;                                 // 32 grp x 32 per-wave flags
  unsigned short* WTs = (unsigned short*)(w + 4096);    // [2048][640]
  unsigned short* WTl = WTs + (size_t)G4 * KD;
  unsigned short* WTo = WTl + (size_t)G4 * KD;          // [512][1024]
  unsigned short* hs0 = WTo + (size_t)HD * 1024;
  unsigned short* hs1 = hs0 + (size_t)512 * HD;
  unsigned short* hl0 = hs1 + (size_t)512 * HD;
  unsigned short* hl1 = hl0 + (size_t)512 * HD;

  prep<<<769, 256, 0, stream>>>(sW, lW, oW, WTs, WTl, WTo, flags);

  const float* xsp = xs; const float* xlp = xl;
  const float* sbp = sb; const float* lbp = lb;
  const unsigned short *WTs_c = WTs, *WTl_c = WTl;
  unsigned short *a_hs0 = hs0, *a_hs1 = hs1, *a_hl0 = hl0, *a_hl1 = hl1;
  int* a_flags = flags;
  void* args[] = {(void*)&xsp, (void*)&xlp, (void*)&WTs_c, (void*)&WTl_c,
                  (void*)&sbp, (void*)&lbp, (void*)&a_hs0, (void*)&a_hs1,
                  (void*)&a_hl0, (void*)&a_hl1, (void*)&a_flags};
  hipError_t e = hipLaunchCooperativeKernel((const void*)lstm_persistent,
                                            dim3(256), dim3(256), args, 0, stream);
  if (e != hipSuccess) {
    lstm_persistent<<<256, 256, 0, stream>>>(xs, xl, WTs, WTl, sb, lb,
                                             hs0, hs1, hl0, hl1, flags);
  }
  // t=127 (odd) wrote h0 buffers
  out_gemm<<<32, 256, 0, stream>>>(hs0, hl0, WTo, ob, (float*)d_out);
}